// Round 2
// baseline (585.063 us; speedup 1.0000x reference)
//
#include <hip/hip_runtime.h>
#include <hip/hip_bf16.h>
#include <cstdint>

// ---------------------------------------------------------------------------
// GraphSAGE inference. bf16 GEMM plane (MFMA, async LDS staging); fp8 e4m3
// aggregation tables; XCD-sliced CSR build.
// Round 9: aggregation kernels get packed-f32 accumulation (v_pk_add_f32)
// and explicit double-buffered gather pipelines (loads for chunk t+1 in
// flight during cvt/acc of chunk t). bin_edges compaction switched from LDS
// atomics (2048/block, 8-way contention) to ballot-rank with wave-uniform
// register bases. Scatter counts DOWN on deg (no cursor array/memset).
// ---------------------------------------------------------------------------

typedef __attribute__((ext_vector_type(8))) short  frag_ab;  // 8 bf16
typedef __attribute__((ext_vector_type(4))) float  f32x4;
typedef __attribute__((ext_vector_type(2))) float  vf2;

#define NSLICE 8
#define BIN_T 2048      // edges per partition tile
#define NCHUNK2 128     // chunks per slice in count/scatter

__device__ __forceinline__ unsigned short f2b(float f) {
    __hip_bfloat16 h = __float2bfloat16(f);
    return *reinterpret_cast<unsigned short*>(&h);
}
__device__ __forceinline__ unsigned char f2p8(float f) {
    int p = __builtin_amdgcn_cvt_pk_fp8_f32(f, f, 0, false);
    return (unsigned char)(p & 0xff);
}
// accumulate 8 bf16 (as uint4) into 4 packed-f32 pairs
__device__ __forceinline__ void acc8_v(vf2* a, uint4 v) {
    vf2 t0; t0.x = __uint_as_float(v.x << 16); t0.y = __uint_as_float(v.x & 0xffff0000u);
    vf2 t1; t1.x = __uint_as_float(v.y << 16); t1.y = __uint_as_float(v.y & 0xffff0000u);
    vf2 t2; t2.x = __uint_as_float(v.z << 16); t2.y = __uint_as_float(v.z & 0xffff0000u);
    vf2 t3; t3.x = __uint_as_float(v.w << 16); t3.y = __uint_as_float(v.w & 0xffff0000u);
    a[0] += t0; a[1] += t1; a[2] += t2; a[3] += t3;
}
// accumulate 16 fp8 (as uint4) into 8 packed-f32 pairs via HW cvt
__device__ __forceinline__ void acc16p_v(vf2* a, uint4 v) {
    a[0] += __builtin_amdgcn_cvt_pk_f32_fp8(v.x, false);
    a[1] += __builtin_amdgcn_cvt_pk_f32_fp8(v.x, true);
    a[2] += __builtin_amdgcn_cvt_pk_f32_fp8(v.y, false);
    a[3] += __builtin_amdgcn_cvt_pk_f32_fp8(v.y, true);
    a[4] += __builtin_amdgcn_cvt_pk_f32_fp8(v.z, false);
    a[5] += __builtin_amdgcn_cvt_pk_f32_fp8(v.z, true);
    a[6] += __builtin_amdgcn_cvt_pk_f32_fp8(v.w, false);
    a[7] += __builtin_amdgcn_cvt_pk_f32_fp8(v.w, true);
}

// async global->LDS, 16B per lane; lds base wave-uniform (HW adds lane*16)
__device__ __forceinline__ void gl_lds16(const void* g, void* l) {
    __builtin_amdgcn_global_load_lds(
        (const __attribute__((address_space(1))) unsigned int*)g,
        (__attribute__((address_space(3))) unsigned int*)l, 16, 0, 0);
}

// ---------------- CSR build: 8-way partition then sliced count/scatter -----
// Pass 1: partition edges into per-slice (dst,src) buckets. One coalesced
// read of the edge list; ballot histogram; one global atomicAdd per
// (tile,slice) for reservation; ballot-rank compaction (no LDS atomics);
// coalesced flush.
__global__ __launch_bounds__(256) void bin_edges(
    const int* __restrict__ src, const int* __restrict__ dst,
    int* __restrict__ bdst, int* __restrict__ bsrc,
    int* __restrict__ gcnt, int E, int sliceW, int cap) {
    __shared__ int lds_d[BIN_T];
    __shared__ int lds_s[BIN_T];
    __shared__ int whist[4][NSLICE];
    __shared__ int tot_s[NSLICE];
    __shared__ int pref[NSLICE + 1];
    __shared__ int gbase[NSLICE];

    const int tid = threadIdx.x;
    const int w = tid >> 6, lane = tid & 63;
    const int e0 = blockIdx.x * BIN_T;
    const int base = e0 + tid * 8;
    const unsigned long long lt = (1ull << lane) - 1ull;

    int d[8], sv[8], sl[8];
    if (e0 + BIN_T <= E) {
        int4 a0 = *reinterpret_cast<const int4*>(dst + base);
        int4 a1 = *reinterpret_cast<const int4*>(dst + base + 4);
        int4 b0 = *reinterpret_cast<const int4*>(src + base);
        int4 b1 = *reinterpret_cast<const int4*>(src + base + 4);
        d[0] = a0.x; d[1] = a0.y; d[2] = a0.z; d[3] = a0.w;
        d[4] = a1.x; d[5] = a1.y; d[6] = a1.z; d[7] = a1.w;
        sv[0] = b0.x; sv[1] = b0.y; sv[2] = b0.z; sv[3] = b0.w;
        sv[4] = b1.x; sv[5] = b1.y; sv[6] = b1.z; sv[7] = b1.w;
#pragma unroll
        for (int j = 0; j < 8; j++)
            sl[j] = (int)((unsigned)d[j] / (unsigned)sliceW);
    } else {
#pragma unroll
        for (int j = 0; j < 8; j++) {
            int e = base + j;
            if (e < E) {
                d[j] = dst[e]; sv[j] = src[e];
                sl[j] = (int)((unsigned)d[j] / (unsigned)sliceW);
            } else {
                d[j] = 0; sv[j] = 0; sl[j] = NSLICE;  // invalid sentinel
            }
        }
    }

    // per-wave histogram via ballots (no LDS atomic contention)
    int wcnt[NSLICE];
#pragma unroll
    for (int s = 0; s < NSLICE; s++) wcnt[s] = 0;
#pragma unroll
    for (int j = 0; j < 8; j++)
#pragma unroll
        for (int s = 0; s < NSLICE; s++)
            wcnt[s] += __popcll(__ballot(sl[j] == s));
    if (lane == 0)
#pragma unroll
        for (int s = 0; s < NSLICE; s++) whist[w][s] = wcnt[s];
    __syncthreads();
    if (tid < NSLICE) {
        int t = whist[0][tid] + whist[1][tid] + whist[2][tid] + whist[3][tid];
        tot_s[tid] = t;
        gbase[tid] = atomicAdd(&gcnt[tid], t);
    }
    __syncthreads();
    if (tid == 0) {
        int acc = 0;
#pragma unroll
        for (int k = 0; k < NSLICE; k++) { pref[k] = acc; acc += tot_s[k]; }
        pref[NSLICE] = acc;
    }
    __syncthreads();
    // wave-uniform running bases (registers; ballots are wave-uniform)
    int bases[NSLICE];
#pragma unroll
    for (int s = 0; s < NSLICE; s++) {
        int b = pref[s];
        if (w > 0) b += whist[0][s];
        if (w > 1) b += whist[1][s];
        if (w > 2) b += whist[2][s];
        bases[s] = b;
    }
    // ballot-rank compaction into LDS
#pragma unroll
    for (int j = 0; j < 8; j++) {
        unsigned long long bal[NSLICE];
#pragma unroll
        for (int s = 0; s < NSLICE; s++) bal[s] = __ballot(sl[j] == s);
        int pos = 0;
#pragma unroll
        for (int s = 0; s < NSLICE; s++) {
            int cand = bases[s] + __popcll(bal[s] & lt);
            pos = (sl[j] == s) ? cand : pos;
        }
        if (sl[j] < NSLICE) {
            lds_d[pos] = d[j];
            lds_s[pos] = sv[j];
        }
#pragma unroll
        for (int s = 0; s < NSLICE; s++) bases[s] += __popcll(bal[s]);
    }
    __syncthreads();
    // coalesced flush: element i belongs to slice s with pref[s]<=i<pref[s+1]
    const int nv = pref[NSLICE];
    for (int i = tid; i < nv; i += 256) {
        int sli = 0;
#pragma unroll
        for (int k = 1; k < NSLICE; k++) sli += (i >= pref[k]);
        int off = gbase[sli] + (i - pref[sli]);
        bdst[(size_t)sli * cap + off] = lds_d[i];
        bsrc[(size_t)sli * cap + off] = lds_s[i];
    }
}

// Pass 2: per-slice degree count. blockIdx&7 -> slice -> XCD-local atomics.
__global__ __launch_bounds__(256) void count_deg_binned(
    const int* __restrict__ bdst, const int* __restrict__ gcnt,
    int* __restrict__ deg, int cap) {
    const int slice = blockIdx.x & (NSLICE - 1);
    const int chunk = blockIdx.x >> 3;
    const int cnt = gcnt[slice];
    const int per = (cnt + NCHUNK2 - 1) / NCHUNK2;
    const int i0 = chunk * per;
    const int i1 = min(i0 + per, cnt);
    const int* b = bdst + (size_t)slice * cap;
    for (int i = i0 + threadIdx.x; i < i1; i += 256)
        atomicAdd(&deg[b[i]], 1);
}

// Pass 4: per-slice scatter into CSR. Counts DOWN on deg (no cursor array).
__global__ __launch_bounds__(256) void scatter_edges_binned(
    const int* __restrict__ bdst, const int* __restrict__ bsrc,
    const int* __restrict__ gcnt, const int* __restrict__ row_start,
    int* __restrict__ deg, int* __restrict__ csr, int cap) {
    const int slice = blockIdx.x & (NSLICE - 1);
    const int chunk = blockIdx.x >> 3;
    const int cnt = gcnt[slice];
    const int per = (cnt + NCHUNK2 - 1) / NCHUNK2;
    const int i0 = chunk * per;
    const int i1 = min(i0 + per, cnt);
    const int* bd = bdst + (size_t)slice * cap;
    const int* bs = bsrc + (size_t)slice * cap;
    for (int i = i0 + threadIdx.x; i < i1; i += 256) {
        int dd = bd[i];
        int ss = bs[i];
        int pos = atomicSub(&deg[dd], 1) - 1;
        csr[row_start[dd] + pos] = ss;
    }
}

__global__ __launch_bounds__(256) void scan_partial_kernel(
    const int* __restrict__ deg, int* __restrict__ partials, int n) {
    const int t = threadIdx.x;
    const int i0 = blockIdx.x * 1024 + t * 4;
    int sum = 0;
#pragma unroll
    for (int j = 0; j < 4; j++) { int i = i0 + j; if (i < n) sum += deg[i]; }
#pragma unroll
    for (int off = 32; off; off >>= 1) sum += __shfl_down(sum, off);
    __shared__ int ws[4];
    int lane = t & 63, wid = t >> 6;
    if (lane == 0) ws[wid] = sum;
    __syncthreads();
    if (t == 0) partials[blockIdx.x] = ws[0] + ws[1] + ws[2] + ws[3];
}

__global__ void scan_partials_kernel(int* __restrict__ p, int nb) {
    const int lane = threadIdx.x;  // 64 threads
    int carry = 0;
    for (int base = 0; base < nb; base += 64) {
        int i = base + lane;
        int v = (i < nb) ? p[i] : 0;
        int orig = v;
#pragma unroll
        for (int off = 1; off < 64; off <<= 1) {
            int x = __shfl_up(v, off);
            if (lane >= off) v += x;
        }
        int ex = carry + v - orig;
        if (i < nb) p[i] = ex;
        carry += __shfl(v, 63);
    }
}

__global__ __launch_bounds__(256) void scan_final_kernel(
    const int* __restrict__ deg, const int* __restrict__ pscan,
    int* __restrict__ row_start, int n) {
    const int t = threadIdx.x;
    const int i0 = blockIdx.x * 1024 + t * 4;
    int v0 = (i0 + 0 < n) ? deg[i0 + 0] : 0;
    int v1 = (i0 + 1 < n) ? deg[i0 + 1] : 0;
    int v2 = (i0 + 2 < n) ? deg[i0 + 2] : 0;
    int v3 = (i0 + 3 < n) ? deg[i0 + 3] : 0;
    int tot = v0 + v1 + v2 + v3;
    int lane = t & 63, wid = t >> 6;
    int inc = tot;
#pragma unroll
    for (int off = 1; off < 64; off <<= 1) {
        int x = __shfl_up(inc, off);
        if (lane >= off) inc += x;
    }
    __shared__ int wsum[4];
    if (lane == 63) wsum[wid] = inc;
    __syncthreads();
    int wbase = 0;
    for (int w2 = 0; w2 < wid; w2++) wbase += wsum[w2];
    int r = wbase + inc - tot + pscan[blockIdx.x];
    r += v0; if (i0 + 0 < n) row_start[i0 + 1] = r;
    r += v1; if (i0 + 1 < n) row_start[i0 + 2] = r;
    r += v2; if (i0 + 2 < n) row_start[i0 + 3] = r;
    r += v3; if (i0 + 3 < n) row_start[i0 + 4] = r;
    if (blockIdx.x == 0 && t == 0) row_start[0] = 0;
}

// ---------------- conversions ----------------
__global__ void conv_x_kernel(const float* __restrict__ in, unsigned short* __restrict__ outb,
                              unsigned char* __restrict__ outp, int n4) {
    int i = blockIdx.x * blockDim.x + threadIdx.x;
    if (i >= n4) return;
    float4 v = *reinterpret_cast<const float4*>(in + (size_t)i * 4);
    ushort4 ob = { f2b(v.x), f2b(v.y), f2b(v.z), f2b(v.w) };
    *reinterpret_cast<ushort4*>(outb + (size_t)i * 4) = ob;
    int p0 = __builtin_amdgcn_cvt_pk_fp8_f32(v.x, v.y, 0, false);
    int p1 = __builtin_amdgcn_cvt_pk_fp8_f32(v.z, v.w, 0, false);
    unsigned int packed = (unsigned int)(p0 & 0xffff) | ((unsigned int)p1 << 16);
    *reinterpret_cast<unsigned int*>(outp + (size_t)i * 4) = packed;
}

// all six weight transposes in one dispatch.
__global__ __launch_bounds__(256) void wt_all_kernel(
    const float* __restrict__ Ws0, const float* __restrict__ Wn0,
    const float* __restrict__ Ws1, const float* __restrict__ Wn1,
    const float* __restrict__ Ws2, const float* __restrict__ Wn2,
    unsigned short* __restrict__ Wt0, unsigned short* __restrict__ Wt1,
    unsigned short* __restrict__ Wt2) {
    int b = blockIdx.x;
    const float* W; unsigned short* Wt; int N, koff, Ktot, noff, idx;
    if (b < 1024) {
        int seg = b >> 8; idx = (b & 255) * 256 + threadIdx.x;
        N = 256; Ktot = 512; noff = 0;
        if (seg == 0)      { W = Ws0; Wt = Wt0; koff = 0;   }
        else if (seg == 1) { W = Wn0; Wt = Wt0; koff = 256; }
        else if (seg == 2) { W = Ws1; Wt = Wt1; koff = 0;   }
        else               { W = Wn1; Wt = Wt1; koff = 256; }
    } else {
        int seg = (b - 1024) >> 6; idx = ((b - 1024) & 63) * 256 + threadIdx.x;
        N = 64; Ktot = 256; koff = 0;
        if (seg == 0) { W = Ws2; Wt = Wt2; noff = 0;  }
        else          { W = Wn2; Wt = Wt2; noff = 64; }
    }
    int k = idx / N, n = idx - k * N;
    Wt[(size_t)(n + noff) * Ktot + koff + k] = f2b(W[(size_t)idx]);
}

// ---------------- aggregation ----------------
// fp8 rows (256B). Quarter-wave q covers one edge's row (16 lanes x 16B).
// Double-buffered: chunk t+1's loads issue before chunk t's cvt/acc.
__global__ __launch_bounds__(256) void agg256_fp8(
    const unsigned char* __restrict__ hsrc, const int* __restrict__ row_start,
    const int* __restrict__ csr, unsigned short* __restrict__ out, int n) {
    int wv = (blockIdx.x * blockDim.x + threadIdx.x) >> 6;
    int lane = threadIdx.x & 63;
    if (wv >= n) return;
    int s0 = row_start[wv], s1 = row_start[wv + 1];
    int deg = s1 - s0;
    const int q  = lane >> 4;
    const int li = lane & 15;
    vf2 a[8];
#pragma unroll
    for (int k = 0; k < 8; k++) a[k] = (vf2)(0.f);

    uint4 v[4];
#pragma unroll
    for (int j = 0; j < 4; j++) {
        int e = s0 + q + 4 * j;
        int idx = csr[e < s1 ? e : s1 - 1];
        v[j] = make_uint4(0u, 0u, 0u, 0u);
        if (e < s1)
            v[j] = *reinterpret_cast<const uint4*>(hsrc + (size_t)idx * 256 + li * 16);
    }
    for (int base = s0 + 16; base < s1; base += 16) {
        uint4 nv[4];
#pragma unroll
        for (int j = 0; j < 4; j++) {
            int e = base + q + 4 * j;
            int idx = csr[e < s1 ? e : s1 - 1];
            nv[j] = make_uint4(0u, 0u, 0u, 0u);
            if (e < s1)
                nv[j] = *reinterpret_cast<const uint4*>(hsrc + (size_t)idx * 256 + li * 16);
        }
#pragma unroll
        for (int j = 0; j < 4; j++) acc16p_v(a, v[j]);
#pragma unroll
        for (int j = 0; j < 4; j++) v[j] = nv[j];
    }
#pragma unroll
    for (int j = 0; j < 4; j++) acc16p_v(a, v[j]);

    float af[16];
#pragma unroll
    for (int p = 0; p < 8; p++) { af[2 * p] = a[p].x; af[2 * p + 1] = a[p].y; }
#pragma unroll
    for (int k = 0; k < 16; k++) {
        af[k] += __shfl_xor(af[k], 16);
        af[k] += __shfl_xor(af[k], 32);
    }
    if (q == 0) {
        float sc = 1.0f / (float)max(deg, 1);
        uint4 o0, o1;
        o0.x = ((unsigned)f2b(af[1]  * sc) << 16) | f2b(af[0]  * sc);
        o0.y = ((unsigned)f2b(af[3]  * sc) << 16) | f2b(af[2]  * sc);
        o0.z = ((unsigned)f2b(af[5]  * sc) << 16) | f2b(af[4]  * sc);
        o0.w = ((unsigned)f2b(af[7]  * sc) << 16) | f2b(af[6]  * sc);
        o1.x = ((unsigned)f2b(af[9]  * sc) << 16) | f2b(af[8]  * sc);
        o1.y = ((unsigned)f2b(af[11] * sc) << 16) | f2b(af[10] * sc);
        o1.z = ((unsigned)f2b(af[13] * sc) << 16) | f2b(af[12] * sc);
        o1.w = ((unsigned)f2b(af[15] * sc) << 16) | f2b(af[14] * sc);
        *reinterpret_cast<uint4*>(out + (size_t)wv * 256 + li * 16) = o0;
        *reinterpret_cast<uint4*>(out + (size_t)wv * 256 + li * 16 + 8) = o1;
    }
}

// h2[v][:] = Sself[v][:] + mean_{s in N(v)} Tb[s][:] + b2 ; Tb bf16 64-wide
__global__ __launch_bounds__(256) void agg64_final(
    const unsigned short* __restrict__ t, const int* __restrict__ row_start,
    const int* __restrict__ csr, const float* __restrict__ Sself,
    const float* __restrict__ b2, float* __restrict__ h2, int n) {
    int wv = (blockIdx.x * blockDim.x + threadIdx.x) >> 6;
    int lane = threadIdx.x & 63;
    if (wv >= n) return;
    int s0 = row_start[wv], s1 = row_start[wv + 1];
    int deg = s1 - s0;
    const int g  = lane >> 3;
    const int li = lane & 7;
    vf2 a[4];
#pragma unroll
    for (int k = 0; k < 4; k++) a[k] = (vf2)(0.f);

    int base = s0 + g;
    const bool have = base < s1;
    uint4 v0 = make_uint4(0u, 0u, 0u, 0u), v1 = v0;
    if (have) {
        int i0 = csr[base];
        v0 = *reinterpret_cast<const uint4*>(t + (size_t)i0 * 64 + li * 8);
        int e1 = base + 8;
        if (e1 < s1) {
            int i1 = csr[e1];
            v1 = *reinterpret_cast<const uint4*>(t + (size_t)i1 * 64 + li * 8);
        }
    }
    for (base += 16; base < s1; base += 16) {
        uint4 n0, n1 = make_uint4(0u, 0u, 0u, 0u);
        {
            int i0 = csr[base];
            n0 = *reinterpret_cast<const uint4*>(t + (size_t)i0 * 64 + li * 8);
            int e1 = base + 8;
            if (e1 < s1) {
                int i1 = csr[e1];
                n1 = *reinterpret_cast<const uint4*>(t + (size_t)i1 * 64 + li * 8);
            }
        }
        acc8_v(a, v0); acc8_v(a, v1);
        v0 = n0; v1 = n1;
    }
    if (have) { acc8_v(a, v0); acc8_v(a, v1); }

    float af[8];
#pragma unroll
    for (int p = 0; p < 4; p++) { af[2 * p] = a[p].x; af[2 * p + 1] = a[p].y; }
#pragma unroll
    for (int k = 0; k < 8; k++) {
        af[k] += __shfl_xor(af[k], 8);
        af[k] += __shfl_xor(af[k], 16);
        af[k] += __shfl_xor(af[k], 32);
    }
    if (g == 0) {
        float sc = 1.0f / (float)max(deg, 1);
        float4 s0v = *reinterpret_cast<const float4*>(Sself + (size_t)wv * 64 + li * 8);
        float4 s1v = *reinterpret_cast<const float4*>(Sself + (size_t)wv * 64 + li * 8 + 4);
        float4 bb0 = *reinterpret_cast<const float4*>(b2 + li * 8);
        float4 bb1 = *reinterpret_cast<const float4*>(b2 + li * 8 + 4);
        float4 o0 = make_float4(s0v.x + af[0] * sc + bb0.x, s0v.y + af[1] * sc + bb0.y,
                                s0v.z + af[2] * sc + bb0.z, s0v.w + af[3] * sc + bb0.w);
        float4 o1 = make_float4(s1v.x + af[4] * sc + bb1.x, s1v.y + af[5] * sc + bb1.y,
                                s1v.z + af[6] * sc + bb1.z, s1v.w + af[7] * sc + bb1.w);
        *reinterpret_cast<float4*>(h2 + (size_t)wv * 64 + li * 8) = o0;
        *reinterpret_cast<float4*>(h2 + (size_t)wv * 64 + li * 8 + 4) = o1;
    }
}

// ---------------- big GEMM: 128x256 row-stripe, 512 threads ----------------
// C[M,256] = relu( [A|G] @ Wt^T + bias ); A,G bf16 [M][256], Wt bf16 [256][512].
// One block covers all 256 cols -> A|G fetched from HBM exactly once.
// Outputs: outB bf16 [M][256] always; outF fp32 (opt); outP fp8 (opt).
#define BTM 128
#define BTN 256
#define BTK 32

__global__ __launch_bounds__(512, 4) void gemm_big512(
    const unsigned short* __restrict__ A, const unsigned short* __restrict__ G,
    const unsigned short* __restrict__ Wt, const float* __restrict__ bias,
    float* __restrict__ outF, unsigned short* __restrict__ outB,
    unsigned char* __restrict__ outP, int M) {
    __shared__ unsigned short Asb[BTM][BTK];   // 8 KB, lane-linear for lds-dma
    __shared__ unsigned short Bsb[BTN][BTK];   // 16 KB

    const int tid = threadIdx.x;
    const int row0 = blockIdx.x * BTM;
    const int w = tid >> 6, lane = tid & 63;
    const int mw = (w & 1) * 64;       // wave m-offset (2 m-groups)
    const int nw = (w >> 1) * 64;      // wave n-offset (4 n-groups)
    const int lm = lane & 15, lq = lane >> 4;
    const int lr = lane >> 2;          // 0..15
    const int lc = (lane & 3) * 8;     // 0/8/16/24 shorts

    f32x4 acc[4][4];
#pragma unroll
    for (int i = 0; i < 4; i++)
#pragma unroll
        for (int j = 0; j < 4; j++) acc[i][j] = (f32x4)(0.f);

    for (int k0 = 0; k0 < 512; k0 += BTK) {
        const unsigned short* __restrict__ Ap = (k0 >= 256) ? G : A;
        const int kl = k0 & 255;
        // A tile: 128 rows x 64B = 8 KB; wave w stages rows [w*16, w*16+16)
        {
            int gr = row0 + w * 16 + lr;
            if (gr < M)
                gl_lds16(Ap + (size_t)gr * 256 + kl + lc, &Asb[w * 16][0]);
        }
        // B tile: 256 rows x 64B = 16 KB; wave w stages rows [w*32, w*32+32)
#pragma unroll
        for (int h = 0; h < 2; ++h) {
            int gn = w * 32 + h * 16 + lr;
            gl_lds16(Wt + (size_t)gn * 512 + k0 + lc, &Bsb[w * 32 + h * 16][0]);
        }
        __syncthreads();

        frag_ab a[4], b[4];
#pragma unroll
        for (int i = 0; i < 4; i++)
            a[i] = *reinterpret_cast<const frag_ab*>(&Asb[mw + i * 16 + lm][lq * 8]);
#pragma unroll
        for (int j = 0; j < 4; j++)
            b[j] = *reinterpret_cast<const frag_ab*>(&Bsb[nw + j * 16 + lm][lq * 8]);
#pragma unroll
        for (int i = 0; i < 4; i++)
#pragma unroll
            for (int j = 0; j < 4; j++)
                acc[i][j] = __builtin_amdgcn_mfma_f32_16x16x32_bf16(a[i], b[j], acc[i][j], 0, 0, 0);
        __syncthreads();
    }

#pragma unroll
    for (int i = 0; i < 4; i++) {
#pragma unroll
        for (int j = 0; j < 4; j++) {
            int cg = nw + j * 16 + lm;
#pragma unroll
            for (int r = 0; r < 4; r++) {
                int rg = row0 + mw + i * 16 + lq * 4 + r;
                if (rg >= M) continue;
                float v = acc[i][j][r] + bias[cg];
                v = fmaxf(v, 0.f);
                outB[(size_t)rg * 256 + cg] = f2b(v);
                if (outF) outF[(size_t)rg * 256 + cg] = v;
                if (outP) outP[(size_t)rg * 256 + cg] = f2p8(v);
            }
        }
    }
}

// ---------------- layer-2 GEMM (256 thr, TN=64 tiles, split epilogue) ------
#define TM 128
#define TN 64
#define TK 32

__global__ __launch_bounds__(256) void gemm_mfma(
    const unsigned short* __restrict__ A, const unsigned short* __restrict__ Wt,
    float* __restrict__ outF, unsigned short* __restrict__ outB, int M) {
    __shared__ unsigned short Asb[TM][TK];
    __shared__ unsigned short Bsb[TN][TK];

    const int tid = threadIdx.x;
    const int row0 = blockIdx.x * TM;
    const int col0 = blockIdx.y * TN;   // 0 -> Sself (fp32), 64 -> Tb (bf16)

    const int w = tid >> 6, lane = tid & 63;
    const int mw = (w & 1) * 64;
    const int nw = (w >> 1) * 32;
    const int lm = lane & 15, lq = lane >> 4;
    const int lr = lane >> 2;
    const int lc = (lane & 3) * 8;

    f32x4 acc[4][2];
#pragma unroll
    for (int i = 0; i < 4; i++)
#pragma unroll
        for (int j = 0; j < 2; j++) acc[i][j] = (f32x4)(0.f);

    for (int k0 = 0; k0 < 256; k0 += TK) {
#pragma unroll
        for (int h = 0; h < 2; ++h) {
            int r16 = w * 32 + h * 16;
            int gr = row0 + r16 + lr;
            if (gr < M)
                gl_lds16(A + (size_t)gr * 256 + k0 + lc, &Asb[r16][0]);
        }
        {
            int n16 = w * 16;
            int gn = col0 + n16 + lr;
            gl_lds16(Wt + (size_t)gn * 256 + k0 + lc, &Bsb[n16][0]);
        }
        __syncthreads();

        frag_ab a[4], b[2];
#pragma unroll
        for (int i = 0; i < 4; i++)
            a[i] = *reinterpret_cast<const frag_ab*>(&Asb[mw + i * 16 + lm][lq * 8]);
#pragma unroll
        for (int j = 0; j < 2; j++)
            b[j] = *reinterpret_cast<const frag_ab*>(&Bsb[nw + j * 16 + lm][lq * 8]);
#pragma unroll
        for (int i = 0; i < 4; i++)
#pragma unroll
            for (int j = 0; j < 2; j++)
                acc[i][j] = __builtin_amdgcn_mfma_f32_16x16x32_bf16(a[i], b[j], acc[i][j], 0, 0, 0);
        __syncthreads();
    }

#pragma unroll
    for (int i = 0; i < 4; i++) {
#pragma unroll
        for (int j = 0; j < 2; j++) {
            int c = nw + j * 16 + lm;   // 0..63 within tile
#pragma unroll
            for (int r = 0; r < 4; r++) {
                int rg = row0 + mw + i * 16 + lq * 4 + r;
                if (rg >= M) continue;
                float v = acc[i][j][r];
                if (col0 == 0) outF[(size_t)rg * 64 + c] = v;
                else           outB[(size_t)rg * 64 + c] = f2b(v);
            }
        }
    }
}

// ---------------------------------------------------------------------------
extern "C" void kernel_launch(void* const* d_in, const int* in_sizes, int n_in,
                              void* d_out, int out_size, void* d_ws, size_t ws_size,
                              hipStream_t stream) {
    const float* x   = (const float*)d_in[0];
    const int*   src = (const int*)d_in[1];
    const int*   dst = (const int*)d_in[2];
    const float* Ws0 = (const float*)d_in[3];
    const float* Wn0 = (const float*)d_in[4];
    const float* b0  = (const float*)d_in[5];
    const float* Ws1 = (const float*)d_in[6];
    const float* Wn1 = (const float*)d_in[7];
    const float* b1  = (const float*)d_in[8];
    const float* Ws2 = (const float*)d_in[9];
    const float* Wn2 = (const float*)d_in[10];
    const float* b2  = (const float*)d_in[11];

    const int N = in_sizes[0] / 256;   // 50000
    const int E = in_sizes[1];         // 1600000

    float* out = (float*)d_out;
    float* h2 = out;                       // N x 64  (output 0)
    float* h1 = out + (size_t)N * 64;      // N x 256 (output 1, fp32)

    // per-slice bucket capacity: E/8 mean + ~60 sigma slack
    const int cap = E / NSLICE + E / (NSLICE * 8) + 2048;

    // ---- workspace layout ----
    char* w = (char*)d_ws;
    auto align16 = [](char* p) { return (char*)(((uintptr_t)p + 15) & ~(uintptr_t)15); };
    int* deg       = (int*)w;  w += (size_t)N * 4;
    int* gcnt      = (int*)w;  w += 16 * 4;            // 8 used, zeroed with deg
    int* row_start = (int*)w;  w += (size_t)(N + 1) * 4;
    int* partials  = (int*)w;  w += 256 * 4;
    int* csr       = (int*)w;  w += (size_t)E * 4;
    int* bdst      = (int*)w;  w += (size_t)NSLICE * cap * 4;
    int* bsrc      = (int*)w;  w += (size_t)NSLICE * cap * 4;
    w = align16(w);
    unsigned short* Wt0   = (unsigned short*)w; w += (size_t)256 * 512 * 2;
    unsigned short* Wt1   = (unsigned short*)w; w += (size_t)256 * 512 * 2;
    unsigned short* Wt2   = (unsigned short*)w; w += (size_t)128 * 256 * 2;  // [Ws2t;Wn2t]
    w = align16(w);
    unsigned short* xb    = (unsigned short*)w; w += (size_t)N * 256 * 2;
    unsigned short* A1b   = (unsigned short*)w; w += (size_t)N * 256 * 2;
    unsigned short* H0b   = (unsigned short*)w; w += (size_t)N * 256 * 2;
    unsigned short* h1b   = (unsigned short*)w; w += (size_t)N * 256 * 2;
    // dead-region aliases (zero extra workspace):
    unsigned char* x8  = (unsigned char*)H0b;  // dead once gemm0 writes H0b
    unsigned char* H08 = (unsigned char*)h1b;  // consumed by agg#2 before gemm1 writes h1b
    unsigned short* Tb    = xb;                // xb dead after gemm0
    float*          Sself = (float*)A1b;       // A1b dead after gemm1

    const int nb = (N + 1023) / 1024;
    const int sliceW = (N + NSLICE - 1) / NSLICE;

    // ---- CSR build: partition -> count -> scan -> scatter ----
    hipMemsetAsync(deg, 0, (size_t)N * 4 + 64, stream);   // deg + gcnt
    {
        int gridBin = (E + BIN_T - 1) / BIN_T;
        bin_edges<<<gridBin, 256, 0, stream>>>(src, dst, bdst, bsrc, gcnt, E, sliceW, cap);
    }
    count_deg_binned<<<NSLICE * NCHUNK2, 256, 0, stream>>>(bdst, gcnt, deg, cap);
    scan_partial_kernel<<<nb, 256, 0, stream>>>(deg, partials, N);
    scan_partials_kernel<<<1, 64, 0, stream>>>(partials, nb);
    scan_final_kernel<<<nb, 256, 0, stream>>>(deg, partials, row_start, N);
    scatter_edges_binned<<<NSLICE * NCHUNK2, 256, 0, stream>>>(bdst, bsrc, gcnt, row_start,
                                                               deg, csr, cap);

    // ---- conversions ----
    {
        int n4 = N * 256 / 4;
        conv_x_kernel<<<(n4 + 255) / 256, 256, 0, stream>>>(x, xb, x8, n4);
    }
    wt_all_kernel<<<1152, 256, 0, stream>>>(Ws0, Wn0, Ws1, Wn1, Ws2, Wn2, Wt0, Wt1, Wt2);

    dim3 aggGrid((N + 3) / 4);
    dim3 gStripe((N + BTM - 1) / BTM);         // 391 blocks x 512 thr
    dim3 gL2((N + TM - 1) / TM, 2);            // 391 x 2 (Sself | Tb)

    // ---- layer 0 ----
    agg256_fp8<<<aggGrid, 256, 0, stream>>>(x8, row_start, csr, A1b, N);
    gemm_big512<<<gStripe, 512, 0, stream>>>(xb, A1b, Wt0, b0, nullptr, H0b, H08, N);
    // ---- layer 1 ----
    agg256_fp8<<<aggGrid, 256, 0, stream>>>(H08, row_start, csr, A1b, N);
    gemm_big512<<<gStripe, 512, 0, stream>>>(H0b, A1b, Wt1, b1, h1, h1b, nullptr, N);
    // ---- layer 2: stacked gemm + fused aggregate/add ----
    gemm_mfma<<<gL2, 256, 0, stream>>>(h1b, Wt2, Sself, Tb, N);
    agg64_final<<<aggGrid, 256, 0, stream>>>(Tb, row_start, csr, Sself, b2, h2, N);
}

// Round 3
// 436.767 us; speedup vs baseline: 1.3395x; 1.3395x over previous
//
#include <hip/hip_runtime.h>
#include <hip/hip_bf16.h>
#include <cstdint>

// ---------------------------------------------------------------------------
// GraphSAGE inference. bf16 GEMM plane (MFMA, async LDS staging); fp8 e4m3
// aggregation tables; node-range-binned CSR build.
// Round 10: CSR build re-binned by 512-node ranges (98 buckets). Degree via
// per-bucket LDS histogram (no global atomics, no deg memset); csr scatter
// via per-bucket LDS cursors into a ~65KB private span that write-combines
// fully in L2 (kills the 59MB->7MB write amplification seen in R9's
// scatter). bin pass: LDS-atomic per-wave hist + ranked placement + flush.
// ---------------------------------------------------------------------------

typedef __attribute__((ext_vector_type(8))) short  frag_ab;  // 8 bf16
typedef __attribute__((ext_vector_type(4))) float  f32x4;
typedef __attribute__((ext_vector_type(2))) float  vf2;

#define BIN_T 4096      // edges per partition tile (512 thr x 8)
#define RSHIFT 9        // 512-node bucket ranges
#define RW 512

__device__ __forceinline__ unsigned short f2b(float f) {
    __hip_bfloat16 h = __float2bfloat16(f);
    return *reinterpret_cast<unsigned short*>(&h);
}
__device__ __forceinline__ unsigned char f2p8(float f) {
    int p = __builtin_amdgcn_cvt_pk_fp8_f32(f, f, 0, false);
    return (unsigned char)(p & 0xff);
}
// accumulate 8 bf16 (as uint4) into 4 packed-f32 pairs
__device__ __forceinline__ void acc8_v(vf2* a, uint4 v) {
    vf2 t0; t0.x = __uint_as_float(v.x << 16); t0.y = __uint_as_float(v.x & 0xffff0000u);
    vf2 t1; t1.x = __uint_as_float(v.y << 16); t1.y = __uint_as_float(v.y & 0xffff0000u);
    vf2 t2; t2.x = __uint_as_float(v.z << 16); t2.y = __uint_as_float(v.z & 0xffff0000u);
    vf2 t3; t3.x = __uint_as_float(v.w << 16); t3.y = __uint_as_float(v.w & 0xffff0000u);
    a[0] += t0; a[1] += t1; a[2] += t2; a[3] += t3;
}
// accumulate 16 fp8 (as uint4) into 8 packed-f32 pairs via HW cvt
__device__ __forceinline__ void acc16p_v(vf2* a, uint4 v) {
    a[0] += __builtin_amdgcn_cvt_pk_f32_fp8(v.x, false);
    a[1] += __builtin_amdgcn_cvt_pk_f32_fp8(v.x, true);
    a[2] += __builtin_amdgcn_cvt_pk_f32_fp8(v.y, false);
    a[3] += __builtin_amdgcn_cvt_pk_f32_fp8(v.y, true);
    a[4] += __builtin_amdgcn_cvt_pk_f32_fp8(v.z, false);
    a[5] += __builtin_amdgcn_cvt_pk_f32_fp8(v.z, true);
    a[6] += __builtin_amdgcn_cvt_pk_f32_fp8(v.w, false);
    a[7] += __builtin_amdgcn_cvt_pk_f32_fp8(v.w, true);
}

// async global->LDS, 16B per lane; lds base wave-uniform (HW adds lane*16)
__device__ __forceinline__ void gl_lds16(const void* g, void* l) {
    __builtin_amdgcn_global_load_lds(
        (const __attribute__((address_space(1))) unsigned int*)g,
        (__attribute__((address_space(3))) unsigned int*)l, 16, 0, 0);
}

// ---------------- CSR build: node-range binning ----------------
// Pass 1: partition edges into per-node-range buckets (dst>>9). Coalesced
// edge read; LDS-atomic per-wave histogram; Hillis-Steele prefix; ranked
// placement; coalesced flush with per-(tile,bucket) global reservation.
__global__ __launch_bounds__(512) void bin_edges(
    const int* __restrict__ src, const int* __restrict__ dst,
    int* __restrict__ bdst, int* __restrict__ bsrc,
    int* __restrict__ gcnt, int E, int cap) {
    __shared__ int lds_d[BIN_T];
    __shared__ int lds_s[BIN_T];
    __shared__ unsigned short lds_b[BIN_T];
    __shared__ int hist[8][128];
    __shared__ int cur[8][128];
    __shared__ int tot[128], scn[128], pref[128], gbase[128];

    const int tid = threadIdx.x;
    const int w = tid >> 6;
    const int e0 = blockIdx.x * BIN_T;
    const int base = e0 + tid * 8;

    int d[8], sv[8], bk[8];
    if (e0 + BIN_T <= E) {
        int4 a0 = *reinterpret_cast<const int4*>(dst + base);
        int4 a1 = *reinterpret_cast<const int4*>(dst + base + 4);
        int4 b0 = *reinterpret_cast<const int4*>(src + base);
        int4 b1 = *reinterpret_cast<const int4*>(src + base + 4);
        d[0] = a0.x; d[1] = a0.y; d[2] = a0.z; d[3] = a0.w;
        d[4] = a1.x; d[5] = a1.y; d[6] = a1.z; d[7] = a1.w;
        sv[0] = b0.x; sv[1] = b0.y; sv[2] = b0.z; sv[3] = b0.w;
        sv[4] = b1.x; sv[5] = b1.y; sv[6] = b1.z; sv[7] = b1.w;
#pragma unroll
        for (int j = 0; j < 8; j++) bk[j] = (int)((unsigned)d[j] >> RSHIFT);
    } else {
#pragma unroll
        for (int j = 0; j < 8; j++) {
            int e = base + j;
            if (e < E) {
                d[j] = dst[e]; sv[j] = src[e];
                bk[j] = (int)((unsigned)d[j] >> RSHIFT);
            } else {
                d[j] = 0; sv[j] = 0; bk[j] = -1;
            }
        }
    }

    // zero histograms
    for (int i = tid; i < 8 * 128; i += 512) ((int*)hist)[i] = 0;
    __syncthreads();
    // per-wave LDS histogram (contention ~ BIN_T/8/98 ~= 5)
#pragma unroll
    for (int j = 0; j < 8; j++)
        if (bk[j] >= 0) atomicAdd(&hist[w][bk[j]], 1);
    __syncthreads();
    // bucket totals + exclusive prefix (Hillis-Steele over 128)
    if (tid < 128) {
        int t = 0;
#pragma unroll
        for (int w2 = 0; w2 < 8; w2++) t += hist[w2][tid];
        tot[tid] = t; scn[tid] = t;
    }
    __syncthreads();
#pragma unroll
    for (int off = 1; off < 128; off <<= 1) {
        int v = 0;
        if (tid < 128 && tid >= off) v = scn[tid - off];
        __syncthreads();
        if (tid < 128 && tid >= off) scn[tid] += v;
        __syncthreads();
    }
    if (tid < 128) {
        pref[tid] = scn[tid] - tot[tid];
        gbase[tid] = atomicAdd(&gcnt[tid], tot[tid]);
        // per-wave cursors
        int b0 = pref[tid];
#pragma unroll
        for (int w2 = 0; w2 < 8; w2++) { cur[w2][tid] = b0; b0 += hist[w2][tid]; }
    }
    __syncthreads();
    // ranked placement into LDS
#pragma unroll
    for (int j = 0; j < 8; j++) {
        if (bk[j] >= 0) {
            int pos = atomicAdd(&cur[w][bk[j]], 1);
            lds_d[pos] = d[j];
            lds_s[pos] = sv[j];
            lds_b[pos] = (unsigned short)bk[j];
        }
    }
    __syncthreads();
    // coalesced flush
    const int nv = scn[127];
    for (int i = tid; i < nv; i += 512) {
        int b = lds_b[i];
        int off = gbase[b] + (i - pref[b]);
        bdst[(size_t)b * cap + off] = lds_d[i];
        bsrc[(size_t)b * cap + off] = lds_s[i];
    }
}

// Pass 2: per-bucket degree histogram in LDS -> coalesced deg write.
__global__ __launch_bounds__(256) void hist_deg(
    const int* __restrict__ bdst, const int* __restrict__ gcnt,
    int* __restrict__ deg, int cap, int N) {
    const int b = blockIdx.x;
    const int cnt = gcnt[b];
    __shared__ int h[RW];
    for (int k = threadIdx.x; k < RW; k += 256) h[k] = 0;
    __syncthreads();
    const int* bd = bdst + (size_t)b * cap;
    for (int i = threadIdx.x; i < cnt; i += 256)
        atomicAdd(&h[bd[i] & (RW - 1)], 1);
    __syncthreads();
    const int v0 = b << RSHIFT;
    for (int k = threadIdx.x; k < RW; k += 256) {
        int node = v0 + k;
        if (node < N) deg[node] = h[k];
    }
}

// Pass 4: per-bucket scatter via LDS cursors seeded from row_start. Writes
// land in the bucket's private ~65KB csr span -> full L2 write combining.
__global__ __launch_bounds__(256) void scatter_direct(
    const int* __restrict__ bdst, const int* __restrict__ bsrc,
    const int* __restrict__ gcnt, const int* __restrict__ row_start,
    int* __restrict__ csr, int cap, int N) {
    const int b = blockIdx.x;
    const int cnt = gcnt[b];
    const int v0 = b << RSHIFT;
    __shared__ int cur[RW];
    for (int k = threadIdx.x; k < RW; k += 256) {
        int node = v0 + k;
        cur[k] = (node < N) ? row_start[node] : 0;
    }
    __syncthreads();
    const int* bd = bdst + (size_t)b * cap;
    const int* bs = bsrc + (size_t)b * cap;
    for (int i = threadIdx.x; i < cnt; i += 256) {
        int dd = bd[i];
        int ss = bs[i];
        int pos = atomicAdd(&cur[dd & (RW - 1)], 1);
        csr[pos] = ss;
    }
}

__global__ __launch_bounds__(256) void scan_partial_kernel(
    const int* __restrict__ deg, int* __restrict__ partials, int n) {
    const int t = threadIdx.x;
    const int i0 = blockIdx.x * 1024 + t * 4;
    int sum = 0;
#pragma unroll
    for (int j = 0; j < 4; j++) { int i = i0 + j; if (i < n) sum += deg[i]; }
#pragma unroll
    for (int off = 32; off; off >>= 1) sum += __shfl_down(sum, off);
    __shared__ int ws[4];
    int lane = t & 63, wid = t >> 6;
    if (lane == 0) ws[wid] = sum;
    __syncthreads();
    if (t == 0) partials[blockIdx.x] = ws[0] + ws[1] + ws[2] + ws[3];
}

__global__ void scan_partials_kernel(int* __restrict__ p, int nb) {
    const int lane = threadIdx.x;  // 64 threads
    int carry = 0;
    for (int base = 0; base < nb; base += 64) {
        int i = base + lane;
        int v = (i < nb) ? p[i] : 0;
        int orig = v;
#pragma unroll
        for (int off = 1; off < 64; off <<= 1) {
            int x = __shfl_up(v, off);
            if (lane >= off) v += x;
        }
        int ex = carry + v - orig;
        if (i < nb) p[i] = ex;
        carry += __shfl(v, 63);
    }
}

__global__ __launch_bounds__(256) void scan_final_kernel(
    const int* __restrict__ deg, const int* __restrict__ pscan,
    int* __restrict__ row_start, int n) {
    const int t = threadIdx.x;
    const int i0 = blockIdx.x * 1024 + t * 4;
    int v0 = (i0 + 0 < n) ? deg[i0 + 0] : 0;
    int v1 = (i0 + 1 < n) ? deg[i0 + 1] : 0;
    int v2 = (i0 + 2 < n) ? deg[i0 + 2] : 0;
    int v3 = (i0 + 3 < n) ? deg[i0 + 3] : 0;
    int tot = v0 + v1 + v2 + v3;
    int lane = t & 63, wid = t >> 6;
    int inc = tot;
#pragma unroll
    for (int off = 1; off < 64; off <<= 1) {
        int x = __shfl_up(inc, off);
        if (lane >= off) inc += x;
    }
    __shared__ int wsum[4];
    if (lane == 63) wsum[wid] = inc;
    __syncthreads();
    int wbase = 0;
    for (int w2 = 0; w2 < wid; w2++) wbase += wsum[w2];
    int r = wbase + inc - tot + pscan[blockIdx.x];
    r += v0; if (i0 + 0 < n) row_start[i0 + 1] = r;
    r += v1; if (i0 + 1 < n) row_start[i0 + 2] = r;
    r += v2; if (i0 + 2 < n) row_start[i0 + 3] = r;
    r += v3; if (i0 + 3 < n) row_start[i0 + 4] = r;
    if (blockIdx.x == 0 && t == 0) row_start[0] = 0;
}

// ---------------- conversions ----------------
__global__ void conv_x_kernel(const float* __restrict__ in, unsigned short* __restrict__ outb,
                              unsigned char* __restrict__ outp, int n4) {
    int i = blockIdx.x * blockDim.x + threadIdx.x;
    if (i >= n4) return;
    float4 v = *reinterpret_cast<const float4*>(in + (size_t)i * 4);
    ushort4 ob = { f2b(v.x), f2b(v.y), f2b(v.z), f2b(v.w) };
    *reinterpret_cast<ushort4*>(outb + (size_t)i * 4) = ob;
    int p0 = __builtin_amdgcn_cvt_pk_fp8_f32(v.x, v.y, 0, false);
    int p1 = __builtin_amdgcn_cvt_pk_fp8_f32(v.z, v.w, 0, false);
    unsigned int packed = (unsigned int)(p0 & 0xffff) | ((unsigned int)p1 << 16);
    *reinterpret_cast<unsigned int*>(outp + (size_t)i * 4) = packed;
}

// all six weight transposes in one dispatch.
__global__ __launch_bounds__(256) void wt_all_kernel(
    const float* __restrict__ Ws0, const float* __restrict__ Wn0,
    const float* __restrict__ Ws1, const float* __restrict__ Wn1,
    const float* __restrict__ Ws2, const float* __restrict__ Wn2,
    unsigned short* __restrict__ Wt0, unsigned short* __restrict__ Wt1,
    unsigned short* __restrict__ Wt2) {
    int b = blockIdx.x;
    const float* W; unsigned short* Wt; int N, koff, Ktot, noff, idx;
    if (b < 1024) {
        int seg = b >> 8; idx = (b & 255) * 256 + threadIdx.x;
        N = 256; Ktot = 512; noff = 0;
        if (seg == 0)      { W = Ws0; Wt = Wt0; koff = 0;   }
        else if (seg == 1) { W = Wn0; Wt = Wt0; koff = 256; }
        else if (seg == 2) { W = Ws1; Wt = Wt1; koff = 0;   }
        else               { W = Wn1; Wt = Wt1; koff = 256; }
    } else {
        int seg = (b - 1024) >> 6; idx = ((b - 1024) & 63) * 256 + threadIdx.x;
        N = 64; Ktot = 256; koff = 0;
        if (seg == 0) { W = Ws2; Wt = Wt2; noff = 0;  }
        else          { W = Wn2; Wt = Wt2; noff = 64; }
    }
    int k = idx / N, n = idx - k * N;
    Wt[(size_t)(n + noff) * Ktot + koff + k] = f2b(W[(size_t)idx]);
}

// ---------------- aggregation ----------------
// fp8 rows (256B). Quarter-wave q covers one edge's row (16 lanes x 16B).
// Double-buffered: chunk t+1's loads issue before chunk t's cvt/acc.
__global__ __launch_bounds__(256) void agg256_fp8(
    const unsigned char* __restrict__ hsrc, const int* __restrict__ row_start,
    const int* __restrict__ csr, unsigned short* __restrict__ out, int n) {
    int wv = (blockIdx.x * blockDim.x + threadIdx.x) >> 6;
    int lane = threadIdx.x & 63;
    if (wv >= n) return;
    int s0 = row_start[wv], s1 = row_start[wv + 1];
    int deg = s1 - s0;
    const int q  = lane >> 4;
    const int li = lane & 15;
    vf2 a[8];
#pragma unroll
    for (int k = 0; k < 8; k++) a[k] = (vf2)(0.f);

    uint4 v[4];
#pragma unroll
    for (int j = 0; j < 4; j++) {
        int e = s0 + q + 4 * j;
        int idx = csr[e < s1 ? e : s1 - 1];
        v[j] = make_uint4(0u, 0u, 0u, 0u);
        if (e < s1)
            v[j] = *reinterpret_cast<const uint4*>(hsrc + (size_t)idx * 256 + li * 16);
    }
    for (int base = s0 + 16; base < s1; base += 16) {
        uint4 nv[4];
#pragma unroll
        for (int j = 0; j < 4; j++) {
            int e = base + q + 4 * j;
            int idx = csr[e < s1 ? e : s1 - 1];
            nv[j] = make_uint4(0u, 0u, 0u, 0u);
            if (e < s1)
                nv[j] = *reinterpret_cast<const uint4*>(hsrc + (size_t)idx * 256 + li * 16);
        }
#pragma unroll
        for (int j = 0; j < 4; j++) acc16p_v(a, v[j]);
#pragma unroll
        for (int j = 0; j < 4; j++) v[j] = nv[j];
    }
#pragma unroll
    for (int j = 0; j < 4; j++) acc16p_v(a, v[j]);

    float af[16];
#pragma unroll
    for (int p = 0; p < 8; p++) { af[2 * p] = a[p].x; af[2 * p + 1] = a[p].y; }
#pragma unroll
    for (int k = 0; k < 16; k++) {
        af[k] += __shfl_xor(af[k], 16);
        af[k] += __shfl_xor(af[k], 32);
    }
    if (q == 0) {
        float sc = 1.0f / (float)max(deg, 1);
        uint4 o0, o1;
        o0.x = ((unsigned)f2b(af[1]  * sc) << 16) | f2b(af[0]  * sc);
        o0.y = ((unsigned)f2b(af[3]  * sc) << 16) | f2b(af[2]  * sc);
        o0.z = ((unsigned)f2b(af[5]  * sc) << 16) | f2b(af[4]  * sc);
        o0.w = ((unsigned)f2b(af[7]  * sc) << 16) | f2b(af[6]  * sc);
        o1.x = ((unsigned)f2b(af[9]  * sc) << 16) | f2b(af[8]  * sc);
        o1.y = ((unsigned)f2b(af[11] * sc) << 16) | f2b(af[10] * sc);
        o1.z = ((unsigned)f2b(af[13] * sc) << 16) | f2b(af[12] * sc);
        o1.w = ((unsigned)f2b(af[15] * sc) << 16) | f2b(af[14] * sc);
        *reinterpret_cast<uint4*>(out + (size_t)wv * 256 + li * 16) = o0;
        *reinterpret_cast<uint4*>(out + (size_t)wv * 256 + li * 16 + 8) = o1;
    }
}

// h2[v][:] = Sself[v][:] + mean_{s in N(v)} Tb[s][:] + b2 ; Tb bf16 64-wide
__global__ __launch_bounds__(256) void agg64_final(
    const unsigned short* __restrict__ t, const int* __restrict__ row_start,
    const int* __restrict__ csr, const float* __restrict__ Sself,
    const float* __restrict__ b2, float* __restrict__ h2, int n) {
    int wv = (blockIdx.x * blockDim.x + threadIdx.x) >> 6;
    int lane = threadIdx.x & 63;
    if (wv >= n) return;
    int s0 = row_start[wv], s1 = row_start[wv + 1];
    int deg = s1 - s0;
    const int g  = lane >> 3;
    const int li = lane & 7;
    vf2 a[4];
#pragma unroll
    for (int k = 0; k < 4; k++) a[k] = (vf2)(0.f);

    int base = s0 + g;
    const bool have = base < s1;
    uint4 v0 = make_uint4(0u, 0u, 0u, 0u), v1 = v0;
    if (have) {
        int i0 = csr[base];
        v0 = *reinterpret_cast<const uint4*>(t + (size_t)i0 * 64 + li * 8);
        int e1 = base + 8;
        if (e1 < s1) {
            int i1 = csr[e1];
            v1 = *reinterpret_cast<const uint4*>(t + (size_t)i1 * 64 + li * 8);
        }
    }
    for (base += 16; base < s1; base += 16) {
        uint4 n0, n1 = make_uint4(0u, 0u, 0u, 0u);
        {
            int i0 = csr[base];
            n0 = *reinterpret_cast<const uint4*>(t + (size_t)i0 * 64 + li * 8);
            int e1 = base + 8;
            if (e1 < s1) {
                int i1 = csr[e1];
                n1 = *reinterpret_cast<const uint4*>(t + (size_t)i1 * 64 + li * 8);
            }
        }
        acc8_v(a, v0); acc8_v(a, v1);
        v0 = n0; v1 = n1;
    }
    if (have) { acc8_v(a, v0); acc8_v(a, v1); }

    float af[8];
#pragma unroll
    for (int p = 0; p < 4; p++) { af[2 * p] = a[p].x; af[2 * p + 1] = a[p].y; }
#pragma unroll
    for (int k = 0; k < 8; k++) {
        af[k] += __shfl_xor(af[k], 8);
        af[k] += __shfl_xor(af[k], 16);
        af[k] += __shfl_xor(af[k], 32);
    }
    if (g == 0) {
        float sc = 1.0f / (float)max(deg, 1);
        float4 s0v = *reinterpret_cast<const float4*>(Sself + (size_t)wv * 64 + li * 8);
        float4 s1v = *reinterpret_cast<const float4*>(Sself + (size_t)wv * 64 + li * 8 + 4);
        float4 bb0 = *reinterpret_cast<const float4*>(b2 + li * 8);
        float4 bb1 = *reinterpret_cast<const float4*>(b2 + li * 8 + 4);
        float4 o0 = make_float4(s0v.x + af[0] * sc + bb0.x, s0v.y + af[1] * sc + bb0.y,
                                s0v.z + af[2] * sc + bb0.z, s0v.w + af[3] * sc + bb0.w);
        float4 o1 = make_float4(s1v.x + af[4] * sc + bb1.x, s1v.y + af[5] * sc + bb1.y,
                                s1v.z + af[6] * sc + bb1.z, s1v.w + af[7] * sc + bb1.w);
        *reinterpret_cast<float4*>(h2 + (size_t)wv * 64 + li * 8) = o0;
        *reinterpret_cast<float4*>(h2 + (size_t)wv * 64 + li * 8 + 4) = o1;
    }
}

// ---------------- big GEMM: 128x256 row-stripe, 512 threads ----------------
// C[M,256] = relu( [A|G] @ Wt^T + bias ); A,G bf16 [M][256], Wt bf16 [256][512].
// One block covers all 256 cols -> A|G fetched from HBM exactly once.
// Outputs: outB bf16 [M][256] always; outF fp32 (opt); outP fp8 (opt).
#define BTM 128
#define BTN 256
#define BTK 32

__global__ __launch_bounds__(512, 4) void gemm_big512(
    const unsigned short* __restrict__ A, const unsigned short* __restrict__ G,
    const unsigned short* __restrict__ Wt, const float* __restrict__ bias,
    float* __restrict__ outF, unsigned short* __restrict__ outB,
    unsigned char* __restrict__ outP, int M) {
    __shared__ unsigned short Asb[BTM][BTK];   // 8 KB, lane-linear for lds-dma
    __shared__ unsigned short Bsb[BTN][BTK];   // 16 KB

    const int tid = threadIdx.x;
    const int row0 = blockIdx.x * BTM;
    const int w = tid >> 6, lane = tid & 63;
    const int mw = (w & 1) * 64;       // wave m-offset (2 m-groups)
    const int nw = (w >> 1) * 64;      // wave n-offset (4 n-groups)
    const int lm = lane & 15, lq = lane >> 4;
    const int lr = lane >> 2;          // 0..15
    const int lc = (lane & 3) * 8;     // 0/8/16/24 shorts

    f32x4 acc[4][4];
#pragma unroll
    for (int i = 0; i < 4; i++)
#pragma unroll
        for (int j = 0; j < 4; j++) acc[i][j] = (f32x4)(0.f);

    for (int k0 = 0; k0 < 512; k0 += BTK) {
        const unsigned short* __restrict__ Ap = (k0 >= 256) ? G : A;
        const int kl = k0 & 255;
        // A tile: 128 rows x 64B = 8 KB; wave w stages rows [w*16, w*16+16)
        {
            int gr = row0 + w * 16 + lr;
            if (gr < M)
                gl_lds16(Ap + (size_t)gr * 256 + kl + lc, &Asb[w * 16][0]);
        }
        // B tile: 256 rows x 64B = 16 KB; wave w stages rows [w*32, w*32+32)
#pragma unroll
        for (int h = 0; h < 2; ++h) {
            int gn = w * 32 + h * 16 + lr;
            gl_lds16(Wt + (size_t)gn * 512 + k0 + lc, &Bsb[w * 32 + h * 16][0]);
        }
        __syncthreads();

        frag_ab a[4], b[4];
#pragma unroll
        for (int i = 0; i < 4; i++)
            a[i] = *reinterpret_cast<const frag_ab*>(&Asb[mw + i * 16 + lm][lq * 8]);
#pragma unroll
        for (int j = 0; j < 4; j++)
            b[j] = *reinterpret_cast<const frag_ab*>(&Bsb[nw + j * 16 + lm][lq * 8]);
#pragma unroll
        for (int i = 0; i < 4; i++)
#pragma unroll
            for (int j = 0; j < 4; j++)
                acc[i][j] = __builtin_amdgcn_mfma_f32_16x16x32_bf16(a[i], b[j], acc[i][j], 0, 0, 0);
        __syncthreads();
    }

#pragma unroll
    for (int i = 0; i < 4; i++) {
#pragma unroll
        for (int j = 0; j < 4; j++) {
            int cg = nw + j * 16 + lm;
#pragma unroll
            for (int r = 0; r < 4; r++) {
                int rg = row0 + mw + i * 16 + lq * 4 + r;
                if (rg >= M) continue;
                float v = acc[i][j][r] + bias[cg];
                v = fmaxf(v, 0.f);
                outB[(size_t)rg * 256 + cg] = f2b(v);
                if (outF) outF[(size_t)rg * 256 + cg] = v;
                if (outP) outP[(size_t)rg * 256 + cg] = f2p8(v);
            }
        }
    }
}

// ---------------- layer-2 GEMM (256 thr, TN=64 tiles, split epilogue) ------
#define TM 128
#define TN 64
#define TK 32

__global__ __launch_bounds__(256) void gemm_mfma(
    const unsigned short* __restrict__ A, const unsigned short* __restrict__ Wt,
    float* __restrict__ outF, unsigned short* __restrict__ outB, int M) {
    __shared__ unsigned short Asb[TM][TK];
    __shared__ unsigned short Bsb[TN][TK];

    const int tid = threadIdx.x;
    const int row0 = blockIdx.x * TM;
    const int col0 = blockIdx.y * TN;   // 0 -> Sself (fp32), 64 -> Tb (bf16)

    const int w = tid >> 6, lane = tid & 63;
    const int mw = (w & 1) * 64;
    const int nw = (w >> 1) * 32;
    const int lm = lane & 15, lq = lane >> 4;
    const int lr = lane >> 2;
    const int lc = (lane & 3) * 8;

    f32x4 acc[4][2];
#pragma unroll
    for (int i = 0; i < 4; i++)
#pragma unroll
        for (int j = 0; j < 2; j++) acc[i][j] = (f32x4)(0.f);

    for (int k0 = 0; k0 < 256; k0 += TK) {
#pragma unroll
        for (int h = 0; h < 2; ++h) {
            int r16 = w * 32 + h * 16;
            int gr = row0 + r16 + lr;
            if (gr < M)
                gl_lds16(A + (size_t)gr * 256 + k0 + lc, &Asb[r16][0]);
        }
        {
            int n16 = w * 16;
            int gn = col0 + n16 + lr;
            gl_lds16(Wt + (size_t)gn * 256 + k0 + lc, &Bsb[n16][0]);
        }
        __syncthreads();

        frag_ab a[4], b[2];
#pragma unroll
        for (int i = 0; i < 4; i++)
            a[i] = *reinterpret_cast<const frag_ab*>(&Asb[mw + i * 16 + lm][lq * 8]);
#pragma unroll
        for (int j = 0; j < 2; j++)
            b[j] = *reinterpret_cast<const frag_ab*>(&Bsb[nw + j * 16 + lm][lq * 8]);
#pragma unroll
        for (int i = 0; i < 4; i++)
#pragma unroll
            for (int j = 0; j < 2; j++)
                acc[i][j] = __builtin_amdgcn_mfma_f32_16x16x32_bf16(a[i], b[j], acc[i][j], 0, 0, 0);
        __syncthreads();
    }

#pragma unroll
    for (int i = 0; i < 4; i++) {
#pragma unroll
        for (int j = 0; j < 2; j++) {
            int c = nw + j * 16 + lm;   // 0..63 within tile
#pragma unroll
            for (int r = 0; r < 4; r++) {
                int rg = row0 + mw + i * 16 + lq * 4 + r;
                if (rg >= M) continue;
                float v = acc[i][j][r];
                if (col0 == 0) outF[(size_t)rg * 64 + c] = v;
                else           outB[(size_t)rg * 64 + c] = f2b(v);
            }
        }
    }
}

// ---------------------------------------------------------------------------
extern "C" void kernel_launch(void* const* d_in, const int* in_sizes, int n_in,
                              void* d_out, int out_size, void* d_ws, size_t ws_size,
                              hipStream_t stream) {
    const float* x   = (const float*)d_in[0];
    const int*   src = (const int*)d_in[1];
    const int*   dst = (const int*)d_in[2];
    const float* Ws0 = (const float*)d_in[3];
    const float* Wn0 = (const float*)d_in[4];
    const float* b0  = (const float*)d_in[5];
    const float* Ws1 = (const float*)d_in[6];
    const float* Wn1 = (const float*)d_in[7];
    const float* b1  = (const float*)d_in[8];
    const float* Ws2 = (const float*)d_in[9];
    const float* Wn2 = (const float*)d_in[10];
    const float* b2  = (const float*)d_in[11];

    const int N = in_sizes[0] / 256;   // 50000
    const int E = in_sizes[1];         // 1600000

    float* out = (float*)d_out;
    float* h2 = out;                       // N x 64  (output 0)
    float* h1 = out + (size_t)N * 64;      // N x 256 (output 1, fp32)

    const int nbuk = (N + RW - 1) >> RSHIFT;              // 98
    const int cap  = (E + nbuk - 1) / nbuk + 2048;        // mean + ~16 sigma

    // ---- workspace layout ----
    char* w = (char*)d_ws;
    auto align16 = [](char* p) { return (char*)(((uintptr_t)p + 15) & ~(uintptr_t)15); };
    int* deg       = (int*)w;  w += (size_t)N * 4;
    int* gcnt      = (int*)w;  w += 128 * 4;
    int* row_start = (int*)w;  w += (size_t)(N + 1) * 4;
    int* partials  = (int*)w;  w += 256 * 4;
    int* csr       = (int*)w;  w += (size_t)E * 4;
    int* bdst      = (int*)w;  w += (size_t)nbuk * cap * 4;
    int* bsrc      = (int*)w;  w += (size_t)nbuk * cap * 4;
    w = align16(w);
    unsigned short* Wt0   = (unsigned short*)w; w += (size_t)256 * 512 * 2;
    unsigned short* Wt1   = (unsigned short*)w; w += (size_t)256 * 512 * 2;
    unsigned short* Wt2   = (unsigned short*)w; w += (size_t)128 * 256 * 2;  // [Ws2t;Wn2t]
    w = align16(w);
    unsigned short* xb    = (unsigned short*)w; w += (size_t)N * 256 * 2;
    unsigned short* A1b   = (unsigned short*)w; w += (size_t)N * 256 * 2;
    unsigned short* H0b   = (unsigned short*)w; w += (size_t)N * 256 * 2;
    unsigned short* h1b   = (unsigned short*)w; w += (size_t)N * 256 * 2;
    // dead-region aliases (zero extra workspace):
    unsigned char* x8  = (unsigned char*)H0b;  // dead once gemm0 writes H0b
    unsigned char* H08 = (unsigned char*)h1b;  // consumed by agg#2 before gemm1 writes h1b
    unsigned short* Tb    = xb;                // xb dead after gemm0
    float*          Sself = (float*)A1b;       // A1b dead after gemm1

    const int nb = (N + 1023) / 1024;

    // ---- CSR build: bin -> hist -> scan -> scatter ----
    hipMemsetAsync(gcnt, 0, 128 * 4, stream);
    bin_edges<<<(E + BIN_T - 1) / BIN_T, 512, 0, stream>>>(src, dst, bdst, bsrc, gcnt, E, cap);
    hist_deg<<<nbuk, 256, 0, stream>>>(bdst, gcnt, deg, cap, N);
    scan_partial_kernel<<<nb, 256, 0, stream>>>(deg, partials, N);
    scan_partials_kernel<<<1, 64, 0, stream>>>(partials, nb);
    scan_final_kernel<<<nb, 256, 0, stream>>>(deg, partials, row_start, N);
    scatter_direct<<<nbuk, 256, 0, stream>>>(bdst, bsrc, gcnt, row_start, csr, cap, N);

    // ---- conversions ----
    {
        int n4 = N * 256 / 4;
        conv_x_kernel<<<(n4 + 255) / 256, 256, 0, stream>>>(x, xb, x8, n4);
    }
    wt_all_kernel<<<1152, 256, 0, stream>>>(Ws0, Wn0, Ws1, Wn1, Ws2, Wn2, Wt0, Wt1, Wt2);

    dim3 aggGrid((N + 3) / 4);
    dim3 gStripe((N + BTM - 1) / BTM);         // 391 blocks x 512 thr
    dim3 gL2((N + TM - 1) / TM, 2);            // 391 x 2 (Sself | Tb)

    // ---- layer 0 ----
    agg256_fp8<<<aggGrid, 256, 0, stream>>>(x8, row_start, csr, A1b, N);
    gemm_big512<<<gStripe, 512, 0, stream>>>(xb, A1b, Wt0, b0, nullptr, H0b, H08, N);
    // ---- layer 1 ----
    agg256_fp8<<<aggGrid, 256, 0, stream>>>(H08, row_start, csr, A1b, N);
    gemm_big512<<<gStripe, 512, 0, stream>>>(H0b, A1b, Wt1, b1, h1, h1b, nullptr, N);
    // ---- layer 2: stacked gemm + fused aggregate/add ----
    gemm_mfma<<<gL2, 256, 0, stream>>>(h1b, Wt2, Sself, Tb, N);
    agg64_final<<<aggGrid, 256, 0, stream>>>(Tb, row_start, csr, Sself, b2, h2, N);
}